// Round 1
// baseline (296.147 us; speedup 1.0000x reference)
//
#include <hip/hip_runtime.h>
#include <math.h>

#define DEVI __device__ __forceinline__

using bf16x8 = __attribute__((ext_vector_type(8))) short;
using f32x4  = __attribute__((ext_vector_type(4))) float;

DEVI float b2f(unsigned short u) {
  union { unsigned int u; float f; } x; x.u = ((unsigned int)u) << 16; return x.f;
}
DEVI unsigned short f2b(float f) {
  union { float f; unsigned int u; } x; x.f = f;
  unsigned int r = (x.u + 0x7fffu + ((x.u >> 16) & 1u)) >> 16;
  return (unsigned short)r;
}
DEVI float gelu_f(float x) { return 0.5f * x * (1.0f + erff(x * 0.70710678118654752440f)); }

// block-wide twin reduction (sum of a, sum of b); NW = waves in block
template<int NW>
DEVI void breduce2(float& a, float& b) {
  __shared__ float buf[2 * NW];
  int lane = threadIdx.x & 63;
  int w = threadIdx.x >> 6;
  #pragma unroll
  for (int off = 32; off > 0; off >>= 1) {
    a += __shfl_down(a, off);
    b += __shfl_down(b, off);
  }
  if (lane == 0) { buf[w] = a; buf[NW + w] = b; }
  __syncthreads();
  float ra = 0.f, rb = 0.f;
  #pragma unroll
  for (int i = 0; i < NW; ++i) { ra += buf[i]; rb += buf[NW + i]; }
  a = ra; b = rb;
  __syncthreads();
}

DEVI void span_params(const int* st, const int* en, int span,
                      int& s, int& e, int& left, int& right) {
  int s0 = st[span], e0 = en[span];
  s = min(max(s0, 0), 511);
  e = max(s, min(e0, 511));
  left = max(0, s - 3);
  right = min(512, e + 4);
}

// ---------------- fp32 -> bf16 weight conversion (vectorized x4) ----------------
__global__ __launch_bounds__(256) void cvt_bf16_kernel(
    const float* __restrict__ in, unsigned short* __restrict__ out, int n4) {
  int i = blockIdx.x * 256 + threadIdx.x;
  if (i < n4) {
    float4 v = reinterpret_cast<const float4*>(in)[i];
    ushort4 o;
    o.x = f2b(v.x); o.y = f2b(v.y); o.z = f2b(v.z); o.w = f2b(v.w);
    reinterpret_cast<ushort4*>(out)[i] = o;
  }
}

// ---------------- per-token LayerNorm of seq_out -> bf16 ----------------
__global__ __launch_bounds__(256) void ln_seq_kernel(
    const float* __restrict__ x, const float* __restrict__ g, const float* __restrict__ bb,
    unsigned short* __restrict__ out) {
  const int row = blockIdx.x;
  const int tid = threadIdx.x;
  const float* xr = x + (size_t)row * 768;
  float v0 = xr[tid], v1 = xr[tid + 256], v2 = xr[tid + 512];
  float s = v0 + v1 + v2;
  float q = v0 * v0 + v1 * v1 + v2 * v2;
  breduce2<4>(s, q);
  float mean = s * (1.0f / 768.0f);
  float var = q * (1.0f / 768.0f) - mean * mean;
  float rstd = rsqrtf(var + 1e-5f);
  unsigned short* orow = out + (size_t)row * 768;
  orow[tid]       = f2b((v0 - mean) * rstd * g[tid]       + bb[tid]);
  orow[tid + 256] = f2b((v1 - mean) * rstd * g[tid + 256] + bb[tid + 256]);
  orow[tid + 512] = f2b((v2 - mean) * rstd * g[tid + 512] + bb[tid + 512]);
}

// ---------------- MFMA bf16 GEMM: C[M,N] = act(A[M,K] @ W[N,K]^T + bias) -> bf16 ----------------
template<int BM, int BN, int WM, int WN, int ACT>
__global__ __launch_bounds__(256) void gemm_bf16(
    const unsigned short* __restrict__ A, const unsigned short* __restrict__ W,
    const float* __restrict__ bias, unsigned short* __restrict__ C,
    int M, int N, int K) {
  constexpr int BK = 32;
  constexpr int LDT = BK + 8;          // padded lds row stride (bf16 elems)
  constexpr int NWC = BN / WN;         // waves along N
  constexpr int FM = WM / 16, FN = WN / 16;
  constexpr int LA = (BM * BK) / (8 * 256);   // uint4 chunks per thread (A)
  constexpr int LB = (BN * BK) / (8 * 256);
  static_assert((BM / WM) * (BN / WN) == 4, "4 waves");
  __shared__ __align__(16) unsigned short As[BM * LDT];
  __shared__ __align__(16) unsigned short Bs[BN * LDT];
  const int tid = threadIdx.x;
  const int lane = tid & 63;
  const int wv = tid >> 6;
  const int wr = wv / NWC, wc = wv % NWC;
  const int l16 = lane & 15, lhi = lane >> 4;
  const int bm = blockIdx.x * BM, bn = blockIdx.y * BN;

  f32x4 acc[FM][FN] = {};

  for (int k0 = 0; k0 < K; k0 += BK) {
    #pragma unroll
    for (int l = 0; l < LA; ++l) {
      int u = tid + l * 256;
      int row = u >> 2, c = u & 3;
      *reinterpret_cast<uint4*>(&As[row * LDT + c * 8]) =
          *reinterpret_cast<const uint4*>(&A[(size_t)(bm + row) * K + k0 + c * 8]);
    }
    #pragma unroll
    for (int l = 0; l < LB; ++l) {
      int u = tid + l * 256;
      int row = u >> 2, c = u & 3;
      *reinterpret_cast<uint4*>(&Bs[row * LDT + c * 8]) =
          *reinterpret_cast<const uint4*>(&W[(size_t)(bn + row) * K + k0 + c * 8]);
    }
    __syncthreads();
    bf16x8 af[FM], bfr[FN];
    #pragma unroll
    for (int fm = 0; fm < FM; ++fm)
      af[fm] = *reinterpret_cast<const bf16x8*>(&As[(wr * WM + fm * 16 + l16) * LDT + lhi * 8]);
    #pragma unroll
    for (int fn = 0; fn < FN; ++fn)
      bfr[fn] = *reinterpret_cast<const bf16x8*>(&Bs[(wc * WN + fn * 16 + l16) * LDT + lhi * 8]);
    #pragma unroll
    for (int fm = 0; fm < FM; ++fm)
      #pragma unroll
      for (int fn = 0; fn < FN; ++fn)
        acc[fm][fn] = __builtin_amdgcn_mfma_f32_16x16x32_bf16(af[fm], bfr[fn], acc[fm][fn], 0, 0, 0);
    __syncthreads();
  }

  // epilogue: D row = (lane>>4)*4 + reg, col = lane&15  [verified C/D layout]
  #pragma unroll
  for (int fm = 0; fm < FM; ++fm) {
    #pragma unroll
    for (int fn = 0; fn < FN; ++fn) {
      int col = bn + wc * WN + fn * 16 + l16;
      float bv = bias[col];
      #pragma unroll
      for (int i = 0; i < 4; ++i) {
        int row = bm + wr * WM + fm * 16 + lhi * 4 + i;
        float v = acc[fm][fn][i] + bv;
        if (ACT) v = gelu_f(v);
        C[(size_t)row * N + col] = f2b(v);
      }
    }
  }
}

// ---------------- ATE finish: LN(h) @ w2^T + b2 -> out[row*2 + c] ----------------
__global__ __launch_bounds__(128) void ate_fin_kernel(
    const unsigned short* __restrict__ h, const float* __restrict__ lng,
    const float* __restrict__ lnb, const float* __restrict__ w2,
    const float* __restrict__ b2, float* __restrict__ out) {
  const int row = blockIdx.x, tid = threadIdx.x;
  const unsigned short* hr = h + (size_t)row * 384;
  float v[3];
  #pragma unroll
  for (int j = 0; j < 3; ++j) v[j] = b2f(hr[tid + j * 128]);
  float s = v[0] + v[1] + v[2];
  float q = v[0] * v[0] + v[1] * v[1] + v[2] * v[2];
  breduce2<2>(s, q);
  float mean = s * (1.f / 384.f);
  float rstd = rsqrtf(q * (1.f / 384.f) - mean * mean + 1e-5f);
  float p0 = 0.f, p1 = 0.f;
  #pragma unroll
  for (int j = 0; j < 3; ++j) {
    int c = tid + j * 128;
    float hl = (v[j] - mean) * rstd * lng[c] + lnb[c];
    p0 += hl * w2[c];
    p1 += hl * w2[384 + c];
  }
  breduce2<2>(p0, p1);
  if (tid == 0) {
    out[(size_t)row * 2]     = p0 + b2[0];
    out[(size_t)row * 2 + 1] = p1 + b2[1];
  }
}

// ---------------- gather context windows -> bf16 rows ----------------
__global__ __launch_bounds__(256) void gather_kernel(
    const float* __restrict__ seq, const int* __restrict__ st, const int* __restrict__ en,
    unsigned short* __restrict__ ctxA) {
  int r = blockIdx.x;           // 0..3839 = span*15 + w
  int span = r / 15, w = r % 15;
  int s, e, left, right;
  span_params(st, en, span, s, e, left, right);
  int b = span >> 2;
  int tok = min(left + w, 511);
  const float* src = seq + ((size_t)b * 512 + tok) * 768;
  unsigned short* dst = ctxA + (size_t)r * 768;
  for (int c = threadIdx.x; c < 768; c += 256) dst[c] = f2b(src[c]);
}

// ---------------- tiny per-span multi-head attention ----------------
__global__ __launch_bounds__(256) void attn_kernel(
    const unsigned short* __restrict__ qkv, const int* __restrict__ st,
    const int* __restrict__ en, unsigned short* __restrict__ ctxO) {
  const int span = blockIdx.x, tid = threadIdx.x;
  int s, e, left, right;
  span_params(st, en, span, s, e, left, right);
  const int nv = right - left;     // 1..15 valid keys
  const int r0 = span * 15;
  __shared__ float qs[15][96], ks[15][96], vs[15][96];
  __shared__ float sc[15][16];
  const float scale = 0.10206207261596576f;   // 1/sqrt(96)
  for (int h = 0; h < 8; ++h) {
    for (int idx = tid; idx < 1440; idx += 256) {
      int w = idx / 96, d = idx % 96;
      const unsigned short* rowp = qkv + (size_t)(r0 + w) * 2304 + h * 96 + d;
      qs[w][d] = b2f(rowp[0]) * scale;
      ks[w][d] = b2f(rowp[768]);
      vs[w][d] = b2f(rowp[1536]);
    }
    __syncthreads();
    if (tid < 225) {
      int i = tid / 15, j = tid % 15;
      float a = 0.f;
      #pragma unroll
      for (int d = 0; d < 96; ++d) a += qs[i][d] * ks[j][d];
      sc[i][j] = (j < nv) ? a : -3.402823466e38f;
    }
    __syncthreads();
    if (tid < 15) {
      int i = tid;
      float m = -3.402823466e38f;
      #pragma unroll
      for (int j = 0; j < 15; ++j) m = fmaxf(m, sc[i][j]);
      float ex[15];
      float ssum = 0.f;
      #pragma unroll
      for (int j = 0; j < 15; ++j) { ex[j] = expf(sc[i][j] - m); ssum += ex[j]; }
      float inv = 1.0f / ssum;
      #pragma unroll
      for (int j = 0; j < 15; ++j) sc[i][j] = ex[j] * inv;
    }
    __syncthreads();
    for (int idx = tid; idx < 1440; idx += 256) {
      int w = idx / 96, d = idx % 96;
      float o = 0.f;
      #pragma unroll
      for (int j = 0; j < 15; ++j) o += sc[w][j] * vs[j][d];
      ctxO[(size_t)(r0 + w) * 768 + h * 96 + d] = f2b(o);
    }
    __syncthreads();
  }
}

// ---------------- masked means -> combined[span][0:768]=asp, [768:1536]=ctx ----------------
__global__ __launch_bounds__(256) void means_kernel(
    const float* __restrict__ seq, const unsigned short* __restrict__ projO,
    const int* __restrict__ st, const int* __restrict__ en,
    unsigned short* __restrict__ comb) {
  const int span = blockIdx.x;
  int s, e, left, right;
  span_params(st, en, span, s, e, left, right);
  int b = span >> 2;
  int e2 = min(e, s + 8);
  int cnt = e2 - s;
  int nv = right - left;
  float inva = (cnt > 0) ? 1.0f / (float)cnt : 0.f;
  float invc = 1.0f / (float)nv;
  for (int c = threadIdx.x; c < 768; c += 256) {
    float sa = 0.f;
    for (int t = s; t < e2; ++t) sa += seq[((size_t)b * 512 + t) * 768 + c];
    float asp = (cnt > 0) ? sa * inva : seq[((size_t)b * 512) * 768 + c];
    comb[(size_t)span * 1536 + c] = f2b(asp);
    float sc_ = 0.f;
    for (int w = 0; w < nv; ++w) sc_ += b2f(projO[(size_t)(span * 15 + w) * 768 + c]);
    comb[(size_t)span * 1536 + 768 + c] = f2b(sc_ * invc);
  }
}

// ---------------- APC: mean over spans -> LN -> classifier -> out[65536 + b*2 + c] ----------------
__global__ __launch_bounds__(256) void apc_kernel(
    const unsigned short* __restrict__ fused, const float* __restrict__ g,
    const float* __restrict__ bb, const float* __restrict__ w1,
    const float* __restrict__ b1, const float* __restrict__ lng,
    const float* __restrict__ lnb, const float* __restrict__ w2,
    const float* __restrict__ b2, float* __restrict__ out) {
  const int b = blockIdx.x, tid = threadIdx.x;
  __shared__ float xs[768];
  __shared__ float hs[384];
  for (int c = tid; c < 768; c += 256) {
    float a = 0.f;
    #pragma unroll
    for (int n = 0; n < 4; ++n) a += b2f(fused[((size_t)(b * 4 + n)) * 768 + c]);
    xs[c] = 0.25f * a;
  }
  __syncthreads();
  float s = 0.f, q = 0.f;
  for (int c = tid; c < 768; c += 256) { float v = xs[c]; s += v; q += v * v; }
  breduce2<4>(s, q);
  float mean = s * (1.f / 768.f);
  float rstd = rsqrtf(q * (1.f / 768.f) - mean * mean + 1e-5f);
  for (int c = tid; c < 768; c += 256) xs[c] = (xs[c] - mean) * rstd * g[c] + bb[c];
  __syncthreads();
  for (int j = tid; j < 384; j += 256) {
    const float* wr = w1 + (size_t)j * 768;
    float a = 0.f;
    for (int k = 0; k < 768; ++k) a += xs[k] * wr[k];
    hs[j] = gelu_f(a + b1[j]);
  }
  __syncthreads();
  s = 0.f; q = 0.f;
  for (int j = tid; j < 384; j += 256) { float v = hs[j]; s += v; q += v * v; }
  breduce2<4>(s, q);
  mean = s * (1.f / 384.f);
  rstd = rsqrtf(q * (1.f / 384.f) - mean * mean + 1e-5f);
  float p0 = 0.f, p1 = 0.f;
  for (int j = tid; j < 384; j += 256) {
    float hl = (hs[j] - mean) * rstd * lng[j] + lnb[j];
    p0 += hl * w2[j];
    p1 += hl * w2[384 + j];
  }
  breduce2<4>(p0, p1);
  if (tid == 0) {
    out[b * 2]     = p0 + b2[0];
    out[b * 2 + 1] = p1 + b2[1];
  }
}

extern "C" void kernel_launch(void* const* d_in, const int* in_sizes, int n_in,
                              void* d_out, int out_size, void* d_ws, size_t ws_size,
                              hipStream_t stream) {
  const float* seq    = (const float*)d_in[0];
  const int*   st     = (const int*)d_in[1];
  const int*   en     = (const int*)d_in[2];
  const float* ate_g  = (const float*)d_in[3];
  const float* ate_b  = (const float*)d_in[4];
  const float* apc_g  = (const float*)d_in[5];
  const float* apc_b  = (const float*)d_in[6];
  const float* w_in   = (const float*)d_in[7];
  const float* b_in   = (const float*)d_in[8];
  const float* w_out  = (const float*)d_in[9];
  const float* b_out  = (const float*)d_in[10];
  const float* fus_w  = (const float*)d_in[11];
  const float* fus_b  = (const float*)d_in[12];
  const float* asp_w1 = (const float*)d_in[13];
  const float* asp_b1 = (const float*)d_in[14];
  const float* asp_lng= (const float*)d_in[15];
  const float* asp_lnb= (const float*)d_in[16];
  const float* asp_w2 = (const float*)d_in[17];
  const float* asp_b2 = (const float*)d_in[18];
  const float* sen_w1 = (const float*)d_in[19];
  const float* sen_b1 = (const float*)d_in[20];
  const float* sen_lng= (const float*)d_in[21];
  const float* sen_lnb= (const float*)d_in[22];
  const float* sen_w2 = (const float*)d_in[23];
  const float* sen_b2 = (const float*)d_in[24];
  float* out = (float*)d_out;

  char* wsb = (char*)d_ws;
  // region1 (50.33 MB): lnx during ATE; later ctxA/ctxO/projO/comb/fused
  unsigned short* lnx   = (unsigned short*)(wsb + 0);
  unsigned short* ctxA  = (unsigned short*)(wsb + 0);
  unsigned short* ctxO  = (unsigned short*)(wsb + 6291456);
  unsigned short* projO = (unsigned short*)(wsb + 12582912);
  unsigned short* comb  = (unsigned short*)(wsb + 18874368);
  unsigned short* fusO  = (unsigned short*)(wsb + 19922944);
  // region2 (25.17 MB): h_ate; later qkv (17.7 MB)
  const size_t off_h = 50331648;
  unsigned short* hate = (unsigned short*)(wsb + off_h);
  unsigned short* qkv  = (unsigned short*)(wsb + off_h);
  // region3: bf16 weights
  const size_t off_w = off_h + 25165824;
  unsigned short* w1b   = (unsigned short*)(wsb + off_w);
  unsigned short* winb  = (unsigned short*)(wsb + off_w + 589824);
  unsigned short* woutb = (unsigned short*)(wsb + off_w + 589824 + 3538944);
  unsigned short* fusb  = (unsigned short*)(wsb + off_w + 589824 + 3538944 + 1179648);

  // weight conversions fp32->bf16
  cvt_bf16_kernel<<<dim3((294912 / 4 + 255) / 256), 256, 0, stream>>>(asp_w1, w1b, 294912 / 4);
  cvt_bf16_kernel<<<dim3((1769472 / 4 + 255) / 256), 256, 0, stream>>>(w_in, winb, 1769472 / 4);
  cvt_bf16_kernel<<<dim3((589824 / 4 + 255) / 256), 256, 0, stream>>>(w_out, woutb, 589824 / 4);
  cvt_bf16_kernel<<<dim3((1179648 / 4 + 255) / 256), 256, 0, stream>>>(fus_w, fusb, 1179648 / 4);

  // ATE path
  ln_seq_kernel<<<32768, 256, 0, stream>>>(seq, ate_g, ate_b, lnx);
  gemm_bf16<128, 128, 64, 64, 1><<<dim3(256, 3), 256, 0, stream>>>(
      lnx, w1b, asp_b1, hate, 32768, 384, 768);
  ate_fin_kernel<<<32768, 128, 0, stream>>>(hate, asp_lng, asp_lnb, asp_w2, asp_b2, out);

  // context path
  gather_kernel<<<3840, 256, 0, stream>>>(seq, st, en, ctxA);
  gemm_bf16<128, 128, 64, 64, 0><<<dim3(30, 18), 256, 0, stream>>>(
      ctxA, winb, b_in, qkv, 3840, 2304, 768);
  attn_kernel<<<256, 256, 0, stream>>>(qkv, st, en, ctxO);
  gemm_bf16<128, 128, 64, 64, 0><<<dim3(30, 6), 256, 0, stream>>>(
      ctxO, woutb, b_out, projO, 3840, 768, 768);
  means_kernel<<<256, 256, 0, stream>>>(seq, projO, st, en, comb);
  gemm_bf16<64, 128, 32, 64, 1><<<dim3(4, 6), 256, 0, stream>>>(
      comb, fusb, fus_b, fusO, 256, 768, 1536);
  apc_kernel<<<64, 256, 0, stream>>>(fusO, apc_g, apc_b, sen_w1, sen_b1,
                                     sen_lng, sen_lnb, sen_w2, sen_b2, out + 65536);
}

// Round 2
// 223.827 us; speedup vs baseline: 1.3231x; 1.3231x over previous
//
#include <hip/hip_runtime.h>
#include <math.h>

#define DEVI __device__ __forceinline__

using bf16x8 = __attribute__((ext_vector_type(8))) short;
using f32x4  = __attribute__((ext_vector_type(4))) float;

DEVI float b2f(unsigned short u) {
  union { unsigned int u; float f; } x; x.u = ((unsigned int)u) << 16; return x.f;
}
DEVI unsigned short f2b(float f) {
  union { float f; unsigned int u; } x; x.f = f;
  unsigned int r = (x.u + 0x7fffu + ((x.u >> 16) & 1u)) >> 16;
  return (unsigned short)r;
}
DEVI float gelu_f(float x) { return 0.5f * x * (1.0f + erff(x * 0.70710678118654752440f)); }

// all-lanes wave reduction of two values (xor butterfly)
DEVI void wredxor2(float& a, float& b) {
  #pragma unroll
  for (int off = 32; off; off >>= 1) {
    a += __shfl_xor(a, off);
    b += __shfl_xor(b, off);
  }
}

// block-wide twin reduction; NW = waves in block (all threads get totals)
template<int NW>
DEVI void breduce2(float& a, float& b) {
  __shared__ float buf[2 * NW];
  int lane = threadIdx.x & 63;
  int w = threadIdx.x >> 6;
  #pragma unroll
  for (int off = 32; off > 0; off >>= 1) {
    a += __shfl_down(a, off);
    b += __shfl_down(b, off);
  }
  if (lane == 0) { buf[w] = a; buf[NW + w] = b; }
  __syncthreads();
  float ra = 0.f, rb = 0.f;
  #pragma unroll
  for (int i = 0; i < NW; ++i) { ra += buf[i]; rb += buf[NW + i]; }
  a = ra; b = rb;
  __syncthreads();
}

DEVI void span_params(const int* st, const int* en, int span,
                      int& s, int& e, int& left, int& right) {
  int s0 = st[span], e0 = en[span];
  s = min(max(s0, 0), 511);
  e = max(s, min(e0, 511));
  left = max(0, s - 3);
  right = min(512, e + 4);
}

// ---------------- combined fp32 -> bf16 weight conversion (5 arrays, float4) ----------------
__global__ __launch_bounds__(256) void cvt_all_kernel(
    const float* __restrict__ s0, const float* __restrict__ s1,
    const float* __restrict__ s2, const float* __restrict__ s3,
    const float* __restrict__ s4,
    unsigned short* __restrict__ d0, unsigned short* __restrict__ d1,
    unsigned short* __restrict__ d2, unsigned short* __restrict__ d3,
    unsigned short* __restrict__ d4) {
  int i = blockIdx.x * 256 + threadIdx.x;
  const float* s; unsigned short* d; int j;
  if (i < 73728)       { s = s0; d = d0; j = i; }
  else if (i < 516096) { s = s1; d = d1; j = i - 73728; }
  else if (i < 663552) { s = s2; d = d2; j = i - 516096; }
  else if (i < 958464) { s = s3; d = d3; j = i - 663552; }
  else                 { s = s4; d = d4; j = i - 958464; }
  float4 v = reinterpret_cast<const float4*>(s)[j];
  ushort4 o;
  o.x = f2b(v.x); o.y = f2b(v.y); o.z = f2b(v.z); o.w = f2b(v.w);
  reinterpret_cast<ushort4*>(d)[j] = o;
}

// ---------------- per-token LayerNorm of seq_out -> bf16 (wave per row, float4) ----------------
__global__ __launch_bounds__(256) void ln_seq_kernel(
    const float* __restrict__ x, const float* __restrict__ g, const float* __restrict__ bb,
    unsigned short* __restrict__ out) {
  const int row = blockIdx.x * 4 + (threadIdx.x >> 6);
  const int lane = threadIdx.x & 63;
  const float4* xr = reinterpret_cast<const float4*>(x + (size_t)row * 768);
  float4 v[3];
  #pragma unroll
  for (int j = 0; j < 3; ++j) v[j] = xr[j * 64 + lane];
  float s = 0.f, q = 0.f;
  #pragma unroll
  for (int j = 0; j < 3; ++j) {
    s += v[j].x + v[j].y + v[j].z + v[j].w;
    q += v[j].x * v[j].x + v[j].y * v[j].y + v[j].z * v[j].z + v[j].w * v[j].w;
  }
  wredxor2(s, q);
  float mean = s * (1.0f / 768.0f);
  float rstd = rsqrtf(q * (1.0f / 768.0f) - mean * mean + 1e-5f);
  ushort4* orow = reinterpret_cast<ushort4*>(out + (size_t)row * 768);
  #pragma unroll
  for (int j = 0; j < 3; ++j) {
    float4 gv = reinterpret_cast<const float4*>(g)[j * 64 + lane];
    float4 bv = reinterpret_cast<const float4*>(bb)[j * 64 + lane];
    ushort4 o;
    o.x = f2b((v[j].x - mean) * rstd * gv.x + bv.x);
    o.y = f2b((v[j].y - mean) * rstd * gv.y + bv.y);
    o.z = f2b((v[j].z - mean) * rstd * gv.z + bv.z);
    o.w = f2b((v[j].w - mean) * rstd * gv.w + bv.w);
    orow[j * 64 + lane] = o;
  }
}

// ---------------- MFMA bf16 GEMM, m97-style global_load_lds staging ----------------
// C[M,N] = act(A[M,K] @ W[N,K]^T + bias) -> bf16
template<int BM, int BN, int WM, int WN, int ACT>
__global__ __launch_bounds__(256) void gemm97(
    const unsigned short* __restrict__ A, const unsigned short* __restrict__ W,
    const float* __restrict__ bias, unsigned short* __restrict__ C,
    int M, int N, int K) {
  constexpr int BK = 32;
  constexpr int NWC = BN / WN;
  constexpr int FM = WM / 16, FN = WN / 16;
  constexpr int CA = BM / 64;   // 1KB staging chunks per wave (A)
  constexpr int CB = BN / 64;
  static_assert((BM / WM) * (BN / WN) == 4, "4 waves");
  __shared__ __align__(16) unsigned short As[BM * BK];
  __shared__ __align__(16) unsigned short Bs[BN * BK];
  const int tid = threadIdx.x;
  const int lane = tid & 63;
  const int wv = tid >> 6;
  const int wr = wv / NWC, wc = wv % NWC;
  const int l16 = lane & 15, lhi = lane >> 4;
  const int bm = blockIdx.x * BM, bn = blockIdx.y * BN;
  const int lr = lane >> 2;          // row within 16-row chunk
  const int lc = (lane & 3) * 8;     // col elems within BK

  f32x4 acc[FM][FN] = {};

  for (int k0 = 0; k0 < K; k0 += BK) {
    #pragma unroll
    for (int c = 0; c < CA; ++c) {
      int ch = wv * CA + c;
      __builtin_amdgcn_global_load_lds(
          (const __attribute__((address_space(1))) void*)&A[(size_t)(bm + ch * 16 + lr) * K + k0 + lc],
          (__attribute__((address_space(3))) void*)&As[ch * 512], 16, 0, 0);
    }
    #pragma unroll
    for (int c = 0; c < CB; ++c) {
      int ch = wv * CB + c;
      __builtin_amdgcn_global_load_lds(
          (const __attribute__((address_space(1))) void*)&W[(size_t)(bn + ch * 16 + lr) * K + k0 + lc],
          (__attribute__((address_space(3))) void*)&Bs[ch * 512], 16, 0, 0);
    }
    __syncthreads();
    bf16x8 af[FM], bfr[FN];
    #pragma unroll
    for (int fm = 0; fm < FM; ++fm)
      af[fm] = *reinterpret_cast<const bf16x8*>(&As[(wr * WM + fm * 16 + l16) * BK + lhi * 8]);
    #pragma unroll
    for (int fn = 0; fn < FN; ++fn)
      bfr[fn] = *reinterpret_cast<const bf16x8*>(&Bs[(wc * WN + fn * 16 + l16) * BK + lhi * 8]);
    #pragma unroll
    for (int fm = 0; fm < FM; ++fm)
      #pragma unroll
      for (int fn = 0; fn < FN; ++fn)
        acc[fm][fn] = __builtin_amdgcn_mfma_f32_16x16x32_bf16(af[fm], bfr[fn], acc[fm][fn], 0, 0, 0);
    __syncthreads();
  }

  // epilogue: D row = (lane>>4)*4 + reg, col = lane&15
  #pragma unroll
  for (int fm = 0; fm < FM; ++fm) {
    #pragma unroll
    for (int fn = 0; fn < FN; ++fn) {
      int col = bn + wc * WN + fn * 16 + l16;
      float bv = bias[col];
      #pragma unroll
      for (int i = 0; i < 4; ++i) {
        int row = bm + wr * WM + fm * 16 + lhi * 4 + i;
        float v = acc[fm][fn][i] + bv;
        if (ACT) v = gelu_f(v);
        C[(size_t)row * N + col] = f2b(v);
      }
    }
  }
}

// ---------------- head finish: LN(h[row,0:384]) @ w2[2,384]^T + b2 -> out[row*2+c] ----------------
// wave per row, grid*4 rows total
__global__ __launch_bounds__(256) void head_fin_kernel(
    const unsigned short* __restrict__ h, const float* __restrict__ lng,
    const float* __restrict__ lnb, const float* __restrict__ w2,
    const float* __restrict__ b2, float* __restrict__ out) {
  const int row = blockIdx.x * 4 + (threadIdx.x >> 6);
  const int lane = threadIdx.x & 63;
  const unsigned short* hr = h + (size_t)row * 384 + lane * 6;
  ushort2 u0 = *reinterpret_cast<const ushort2*>(hr);
  ushort2 u1 = *reinterpret_cast<const ushort2*>(hr + 2);
  ushort2 u2 = *reinterpret_cast<const ushort2*>(hr + 4);
  float v[6] = { b2f(u0.x), b2f(u0.y), b2f(u1.x), b2f(u1.y), b2f(u2.x), b2f(u2.y) };
  float s = 0.f, q = 0.f;
  #pragma unroll
  for (int j = 0; j < 6; ++j) { s += v[j]; q += v[j] * v[j]; }
  wredxor2(s, q);
  float mean = s * (1.f / 384.f);
  float rstd = rsqrtf(q * (1.f / 384.f) - mean * mean + 1e-5f);
  const int c0 = lane * 6;
  float p0 = 0.f, p1 = 0.f;
  #pragma unroll
  for (int j = 0; j < 6; ++j) {
    float hl = (v[j] - mean) * rstd * lng[c0 + j] + lnb[c0 + j];
    p0 += hl * w2[c0 + j];
    p1 += hl * w2[384 + c0 + j];
  }
  wredxor2(p0, p1);
  if (lane == 0) {
    out[(size_t)row * 2]     = p0 + b2[0];
    out[(size_t)row * 2 + 1] = p1 + b2[1];
  }
}

// ---------------- gather context windows -> bf16 rows (float4) ----------------
__global__ __launch_bounds__(192) void gather_kernel(
    const float* __restrict__ seq, const int* __restrict__ st, const int* __restrict__ en,
    unsigned short* __restrict__ ctxA) {
  int r = blockIdx.x;           // 0..3839 = span*15 + w
  int span = r / 15, w = r % 15;
  int s, e, left, right;
  span_params(st, en, span, s, e, left, right);
  int b = span >> 2;
  int tok = min(left + w, 511);
  const float4* src = reinterpret_cast<const float4*>(seq + ((size_t)b * 512 + tok) * 768);
  ushort4* dst = reinterpret_cast<ushort4*>(ctxA + (size_t)r * 768);
  float4 v = src[threadIdx.x];
  ushort4 o;
  o.x = f2b(v.x); o.y = f2b(v.y); o.z = f2b(v.z); o.w = f2b(v.w);
  dst[threadIdx.x] = o;
}

// ---------------- tiny per-(span,head) attention ----------------
__global__ __launch_bounds__(256) void attn_kernel(
    const unsigned short* __restrict__ qkv, const int* __restrict__ st,
    const int* __restrict__ en, unsigned short* __restrict__ ctxO) {
  const int span = blockIdx.x >> 3, h = blockIdx.x & 7;
  const int tid = threadIdx.x;
  int s, e, left, right;
  span_params(st, en, span, s, e, left, right);
  const int nv = right - left;     // 1..15 valid keys
  const int r0 = span * 15;
  __shared__ float qs[15][96], ks[15][96], vs[15][96];
  __shared__ float sc[15][16];
  const float scale = 0.10206207261596576f;   // 1/sqrt(96)
  // load q/k/v for this head: 15 rows x 96, as bf16x8 chunks (180 chunks)
  if (tid < 180) {
    int w = tid / 12, dp = tid % 12, d = dp * 8;
    const unsigned short* rowp = qkv + (size_t)(r0 + w) * 2304 + h * 96 + d;
    bf16x8 qv = *reinterpret_cast<const bf16x8*>(rowp);
    bf16x8 kv = *reinterpret_cast<const bf16x8*>(rowp + 768);
    bf16x8 vv = *reinterpret_cast<const bf16x8*>(rowp + 1536);
    #pragma unroll
    for (int j = 0; j < 8; ++j) {
      qs[w][d + j] = b2f((unsigned short)qv[j]) * scale;
      ks[w][d + j] = b2f((unsigned short)kv[j]);
      vs[w][d + j] = b2f((unsigned short)vv[j]);
    }
  }
  __syncthreads();
  if (tid < 225) {
    int i = tid / 15, j = tid % 15;
    float a = 0.f;
    #pragma unroll
    for (int d = 0; d < 96; ++d) a += qs[i][d] * ks[j][d];
    sc[i][j] = (j < nv) ? a : -3.402823466e38f;
  }
  __syncthreads();
  if (tid < 15) {
    int i = tid;
    float m = -3.402823466e38f;
    #pragma unroll
    for (int j = 0; j < 15; ++j) m = fmaxf(m, sc[i][j]);
    float ex[15];
    float ssum = 0.f;
    #pragma unroll
    for (int j = 0; j < 15; ++j) { ex[j] = expf(sc[i][j] - m); ssum += ex[j]; }
    float inv = 1.0f / ssum;
    #pragma unroll
    for (int j = 0; j < 15; ++j) sc[i][j] = ex[j] * inv;
  }
  __syncthreads();
  for (int idx = tid; idx < 720; idx += 256) {
    int w = idx / 48, dp = idx % 48, d = dp * 2;
    float o0 = 0.f, o1 = 0.f;
    #pragma unroll
    for (int j = 0; j < 15; ++j) {
      float p = sc[w][j];
      o0 += p * vs[j][d];
      o1 += p * vs[j][d + 1];
    }
    ushort2 o; o.x = f2b(o0); o.y = f2b(o1);
    *reinterpret_cast<ushort2*>(&ctxO[(size_t)(r0 + w) * 768 + h * 96 + d]) = o;
  }
}

// ---------------- masked means -> combined[span][0:768]=asp, [768:1536]=ctx ----------------
__global__ __launch_bounds__(256) void means_kernel(
    const float* __restrict__ seq, const unsigned short* __restrict__ projO,
    const int* __restrict__ st, const int* __restrict__ en,
    unsigned short* __restrict__ comb) {
  const int span = blockIdx.x;
  int s, e, left, right;
  span_params(st, en, span, s, e, left, right);
  int b = span >> 2;
  int e2 = min(e, s + 8);
  int cnt = e2 - s;
  int nv = right - left;
  float inva = (cnt > 0) ? 1.0f / (float)cnt : 0.f;
  float invc = 1.0f / (float)nv;
  for (int c = threadIdx.x; c < 768; c += 256) {
    float sa = 0.f;
    for (int t = s; t < e2; ++t) sa += seq[((size_t)b * 512 + t) * 768 + c];
    float asp = (cnt > 0) ? sa * inva : seq[((size_t)b * 512) * 768 + c];
    comb[(size_t)span * 1536 + c] = f2b(asp);
    float sc_ = 0.f;
    for (int w = 0; w < nv; ++w) sc_ += b2f(projO[(size_t)(span * 15 + w) * 768 + c]);
    comb[(size_t)span * 1536 + 768 + c] = f2b(sc_ * invc);
  }
}

// ---------------- APC stage 1: mean over spans -> LN -> bf16 x[64][768] ----------------
__global__ __launch_bounds__(256) void apc_mean_ln_kernel(
    const unsigned short* __restrict__ fused, const float* __restrict__ g,
    const float* __restrict__ bb, unsigned short* __restrict__ outx) {
  const int b = blockIdx.x, tid = threadIdx.x;
  float v[3];
  #pragma unroll
  for (int j = 0; j < 3; ++j) {
    int c = tid + j * 256;
    float a = 0.f;
    #pragma unroll
    for (int n = 0; n < 4; ++n) a += b2f(fused[((size_t)(b * 4 + n)) * 768 + c]);
    v[j] = 0.25f * a;
  }
  float s = v[0] + v[1] + v[2];
  float q = v[0] * v[0] + v[1] * v[1] + v[2] * v[2];
  breduce2<4>(s, q);
  float mean = s * (1.f / 768.f);
  float rstd = rsqrtf(q * (1.f / 768.f) - mean * mean + 1e-5f);
  #pragma unroll
  for (int j = 0; j < 3; ++j) {
    int c = tid + j * 256;
    outx[(size_t)b * 768 + c] = f2b((v[j] - mean) * rstd * g[c] + bb[c]);
  }
}

extern "C" void kernel_launch(void* const* d_in, const int* in_sizes, int n_in,
                              void* d_out, int out_size, void* d_ws, size_t ws_size,
                              hipStream_t stream) {
  const float* seq    = (const float*)d_in[0];
  const int*   st     = (const int*)d_in[1];
  const int*   en     = (const int*)d_in[2];
  const float* ate_g  = (const float*)d_in[3];
  const float* ate_b  = (const float*)d_in[4];
  const float* apc_g  = (const float*)d_in[5];
  const float* apc_b  = (const float*)d_in[6];
  const float* w_in   = (const float*)d_in[7];
  const float* b_in   = (const float*)d_in[8];
  const float* w_out  = (const float*)d_in[9];
  const float* b_out  = (const float*)d_in[10];
  const float* fus_w  = (const float*)d_in[11];
  const float* fus_b  = (const float*)d_in[12];
  const float* asp_w1 = (const float*)d_in[13];
  const float* asp_b1 = (const float*)d_in[14];
  const float* asp_lng= (const float*)d_in[15];
  const float* asp_lnb= (const float*)d_in[16];
  const float* asp_w2 = (const float*)d_in[17];
  const float* asp_b2 = (const float*)d_in[18];
  const float* sen_w1 = (const float*)d_in[19];
  const float* sen_b1 = (const float*)d_in[20];
  const float* sen_lng= (const float*)d_in[21];
  const float* sen_lnb= (const float*)d_in[22];
  const float* sen_w2 = (const float*)d_in[23];
  const float* sen_b2 = (const float*)d_in[24];
  float* out = (float*)d_out;

  char* wsb = (char*)d_ws;
  // region1 (50.33 MB): lnx during ATE; later ctx buffers
  unsigned short* lnx   = (unsigned short*)(wsb + 0);
  unsigned short* ctxA  = (unsigned short*)(wsb + 0);          // alias, lnx dead after gemm1
  unsigned short* ctxO  = (unsigned short*)(wsb + 6291456);
  unsigned short* projO = (unsigned short*)(wsb + 12582912);
  unsigned short* comb  = (unsigned short*)(wsb + 18874368);
  unsigned short* fusO  = (unsigned short*)(wsb + 19922944);
  unsigned short* apcx  = (unsigned short*)(wsb + 20447232);
  unsigned short* apch  = (unsigned short*)(wsb + 20643840);
  // region2 (25.17 MB): hate; later qkv alias (hate dead after head_fin)
  const size_t off_h = 50331648;
  unsigned short* hate = (unsigned short*)(wsb + off_h);
  unsigned short* qkvb = (unsigned short*)(wsb + off_h);
  // region3: bf16 weights
  const size_t off_w = off_h + 25165824;
  unsigned short* w1b   = (unsigned short*)(wsb + off_w);
  unsigned short* winb  = (unsigned short*)(wsb + off_w + 589824);
  unsigned short* woutb = (unsigned short*)(wsb + off_w + 4128768);
  unsigned short* fusb  = (unsigned short*)(wsb + off_w + 5308416);
  unsigned short* senb  = (unsigned short*)(wsb + off_w + 7667712);

  // weight conversions fp32->bf16 (one kernel; 1032192 float4 chunks)
  cvt_all_kernel<<<4032, 256, 0, stream>>>(asp_w1, w_in, w_out, fus_w, sen_w1,
                                           w1b, winb, woutb, fusb, senb);

  // ATE path
  ln_seq_kernel<<<8192, 256, 0, stream>>>(seq, ate_g, ate_b, lnx);
  gemm97<128, 128, 64, 64, 1><<<dim3(256, 3), 256, 0, stream>>>(
      lnx, w1b, asp_b1, hate, 32768, 384, 768);
  head_fin_kernel<<<8192, 256, 0, stream>>>(hate, asp_lng, asp_lnb, asp_w2, asp_b2, out);

  // context path
  gather_kernel<<<3840, 192, 0, stream>>>(seq, st, en, ctxA);
  gemm97<128, 128, 64, 64, 0><<<dim3(30, 18), 256, 0, stream>>>(
      ctxA, winb, b_in, qkvb, 3840, 2304, 768);
  attn_kernel<<<2048, 256, 0, stream>>>(qkvb, st, en, ctxO);
  gemm97<128, 128, 64, 64, 0><<<dim3(30, 6), 256, 0, stream>>>(
      ctxO, woutb, b_out, projO, 3840, 768, 768);
  means_kernel<<<256, 256, 0, stream>>>(seq, projO, st, en, comb);
  gemm97<64, 128, 32, 64, 1><<<dim3(4, 6), 256, 0, stream>>>(
      comb, fusb, fus_b, fusO, 256, 768, 1536);

  // APC path
  apc_mean_ln_kernel<<<64, 256, 0, stream>>>(fusO, apc_g, apc_b, apcx);
  gemm97<64, 128, 32, 64, 1><<<dim3(1, 3), 256, 0, stream>>>(
      apcx, senb, sen_b1, apch, 64, 384, 768);
  head_fin_kernel<<<16, 256, 0, stream>>>(apch, sen_lng, sen_lnb, sen_w2, sen_b2, out + 65536);
}